// Round 6
// baseline (8845.876 us; speedup 1.0000x reference)
//
#include <hip/hip_runtime.h>

// Dims fixed by the reference
#define LAY 2
#define BATCH 64
#define TMAX 512
#define DIM 256
#define ROWS 16            // batch rows per workgroup
#define NWG  (BATCH / ROWS)
#define SLAB 65536         // BYTES per packed fp8 matrix (256x256)
#define AST  264           // LDS activation row stride (bytes, fp8); 264 = 8*33 (b64-aligned rows)

typedef float floatx4 __attribute__((ext_vector_type(4)));
typedef long  longx2  __attribute__((ext_vector_type(2)));
#define MFMA_FP8 __builtin_amdgcn_mfma_f32_16x16x32_fp8_fp8

__device__ __forceinline__ unsigned int pk2(float a, float b) {
    // two fp32 -> two OCP e4m3 bytes in [7:0],[15:8]
    return (unsigned int)__builtin_amdgcn_cvt_pk_fp8_f32(a, b, 0, false);
}
__device__ __forceinline__ unsigned char f2q(float a) { return (unsigned char)(pk2(a, a) & 0xff); }
__device__ __forceinline__ float sigf(float x) { return 1.f / (1.f + __expf(-x)); }

// ---------------------------------------------------------------------------
// Weight prep (unchanged from R5): fp32 [L][256][256] ([k][n] row-major) ->
// e4m3 (x8 scale) packed so ONE wave dwordx4 load fetches TWO k-fragments of
// a 16-col tile:
//   byte addr = ((mat*16+nt)*4 + kp)*1024 + lane*16 + half*8 + j
//   holds 8*W[l][ k=(2kp+half)*32 + (lane>>4)*8 + j ][ n=nt*16 + (lane&15) ]
// ---------------------------------------------------------------------------
__global__ void prep_weights(const float* __restrict__ Wz, const float* __restrict__ Wr,
                             const float* __restrict__ Uz, const float* __restrict__ Ur,
                             const float* __restrict__ Wh, const float* __restrict__ Uh,
                             unsigned short* __restrict__ wp, float* __restrict__ out) {
    int t = blockIdx.x * 256 + threadIdx.x;  // N = 393216
    if (t == 0) out[0] = 0.f;
    int e    = t & 3;            // j pair: j0=2e, j1=2e+1
    int half = (t >> 2) & 1;
    int lane = (t >> 3) & 63;
    int kp   = (t >> 9) & 3;
    int nt   = (t >> 11) & 15;
    int mat  = t >> 15;          // l*6 + m
    int m = mat % 6;
    int l = mat / 6;
    const float* src;
    switch (m) {                 // 0=Wz 1=Wr 2=Uz 3=Ur 4=Wh 5=Uh
        case 0: src = Wz; break;
        case 1: src = Wr; break;
        case 2: src = Uz; break;
        case 3: src = Ur; break;
        case 4: src = Wh; break;
        default: src = Uh; break;
    }
    int n  = nt * 16 + (lane & 15);
    int k0 = (2 * kp + half) * 32 + (lane >> 4) * 8 + 2 * e;
    float w0 = src[(l << 16) + (k0 << 8) + n] * 8.f;        // x8: dodge e4m3 denormals
    float w1 = src[(l << 16) + ((k0 + 1) << 8) + n] * 8.f;  // undone by 0.125 post-acc
    wp[t] = (unsigned short)(pk2(w0, w1) & 0xffff);
}

// One 16-col tile: 4 dwordx4 weight loads (1KB/wave each, single base + imm
// offsets), 8 fp8 MFMAs on one acc chain. K-order identical to R5's a0 chain.
__device__ __forceinline__ void gemm1(const unsigned char* __restrict__ wl, int m,
                                      int nt, int lane, const long* __restrict__ Af,
                                      floatx4& a0) {
    const longx2* p = (const longx2*)(wl + m * SLAB + nt * 4096) + lane;
    longx2 c[4];
#pragma unroll
    for (int kp = 0; kp < 4; ++kp) c[kp] = p[kp * 64];
#pragma unroll
    for (int kp = 0; kp < 4; ++kp) {
        a0 = MFMA_FP8(Af[2 * kp],     c[kp].x, a0, 0, 0, 0);
        a0 = MFMA_FP8(Af[2 * kp + 1], c[kp].y, a0, 0, 0, 0);
    }
}

// 4 WGs x 16 batch rows, 16 waves (1024 thr, 4/SIMD for TLP); wave w owns the
// 16-col tile [16w,16w+16). S1 fp32 master in registers (lane owns its
// C-fragment cells). Phase 1 = 5 gemms (z,r,Wh) + Uh weight prefetch; barrier;
// phase 2 = Uh MFMA + epilogue. Numerics bit-identical to R5.
__global__ __launch_bounds__(1024, 4) void gru_main(const float* __restrict__ x,
                                                    const int* __restrict__ xlen,
                                                    const float* __restrict__ xlab,
                                                    const unsigned char* __restrict__ wp,
                                                    const float* __restrict__ Wo,
                                                    float* __restrict__ out) {
    __shared__ __align__(16) unsigned char s1q[LAY][ROWS][AST];  // S1 (fp8)
    __shared__ __align__(16) unsigned char xq[2][ROWS][AST];     // x_t double buffer (fp8)
    __shared__ __align__(16) unsigned char rsq[ROWS][AST];       // r*S1 (fp8)
    __shared__ __align__(16) float s1o[ROWS][264];               // layer-1 S1 fp32 (score)
    __shared__ float wo1s[DIM];

    const int tid  = threadIdx.x;
    const int wave = tid >> 6;
    const int lane = tid & 63;
    const int l15  = lane & 15;
    const int quad = lane >> 4;
    const int b0   = blockIdx.x * ROWS;

    // ---- init ----
    for (int i = tid; i < LAY * ROWS * AST; i += 1024) ((unsigned char*)s1q)[i] = 0;
    if (tid < DIM) wo1s[tid] = Wo[2 * tid + 1];
    {   // x_0 -> xq[0]; wave w loads batch row w (coalesced dwordx4)
        float4 xv = *(const float4*)&x[((size_t)(b0 + wave) * TMAX + 0) * DIM + lane * 4];
        unsigned int u = pk2(xv.x, xv.y) | (pk2(xv.z, xv.w) << 16);
        *(unsigned int*)&xq[0][wave][lane * 4] = u;
    }
    const int   lenr = xlen[b0 + l15];
    const float labr = xlab[b0 + l15];
    int v = lenr;
#pragma unroll
    for (int o = 1; o < 16; o <<= 1) v = max(v, __shfl_xor(v, o));
    const int tmax = __builtin_amdgcn_readfirstlane(v);

    const int nt   = wave;
    const int colA = nt * 16 + l15;
    const int rowb = quad * 4;
    float s1r[LAY][4];  // fp32 master S1 for this lane's C-fragment cells
#pragma unroll
    for (int l = 0; l < LAY; ++l)
#pragma unroll
        for (int i = 0; i < 4; ++i) s1r[l][i] = 0.f;
    float accl = 0.f;
    __syncthreads();

    for (int t = 0; t < tmax; ++t) {
        const int buf = t & 1;
        for (int l = 0; l < LAY; ++l) {
            const unsigned char* Xs = (l == 0) ? &xq[buf][0][0] : &s1q[0][0][0];
            const unsigned char* Ss = &s1q[l][0][0];
            const unsigned char* wl = wp + (size_t)l * 6 * SLAB;

            // A-fragments (8B/lane b64 reads), reused across the layer's matmuls
            long xf[8], sf[8];
#pragma unroll
            for (int k = 0; k < 8; ++k) {
                xf[k] = *(const long*)&Xs[l15 * AST + k * 32 + quad * 8];
                sf[k] = *(const long*)&Ss[l15 * AST + k * 32 + quad * 8];
            }

            // ---- phase 1: z, r, Wh·X (5 gemms, one tile each) ----
            floatx4 za = {0.f, 0.f, 0.f, 0.f}, ra = za, ha = za;
            gemm1(wl, 0, nt, lane, xf, za);  // X @ Wz
            gemm1(wl, 2, nt, lane, sf, za);  // S @ Uz
            gemm1(wl, 1, nt, lane, xf, ra);  // X @ Wr
            gemm1(wl, 3, nt, lane, sf, ra);  // S @ Ur
            gemm1(wl, 4, nt, lane, xf, ha);  // X @ Wh

            // prefetch Uh weight tile across the barrier (static addresses)
            longx2 c5[4];
            {
                const longx2* p5 = (const longx2*)(wl + 5 * SLAB + nt * 4096) + lane;
#pragma unroll
                for (int kp = 0; kp < 4; ++kp) c5[kp] = p5[kp * 64];
            }

            // prefetch x_{t+1} during layer 0 (writes the idle xq buffer)
            if (l == 0 && t + 1 < tmax) {
                float4 xv = *(const float4*)&x[((size_t)(b0 + wave) * TMAX + (t + 1)) * DIM + lane * 4];
                unsigned int u = pk2(xv.x, xv.y) | (pk2(xv.z, xv.w) << 16);
                *(unsigned int*)&xq[1 - buf][wave][lane * 4] = u;
            }

            float z[4];
#pragma unroll
            for (int i = 0; i < 4; ++i) {
                z[i] = sigf(0.125f * za[i]);
                rsq[rowb + i][colA] = f2q(sigf(0.125f * ra[i]) * s1r[l][i]);
            }
            __syncthreads();

            // ---- phase 2: + (r*S) @ Uh, then epilogue ----
            long rf[8];
#pragma unroll
            for (int k = 0; k < 8; ++k)
                rf[k] = *(const long*)&rsq[0][0 + l15 * AST + k * 32 + quad * 8];
#pragma unroll
            for (int kp = 0; kp < 4; ++kp) {
                ha = MFMA_FP8(rf[2 * kp],     c5[kp].x, ha, 0, 0, 0);
                ha = MFMA_FP8(rf[2 * kp + 1], c5[kp].y, ha, 0, 0, 0);
            }

#pragma unroll
            for (int i = 0; i < 4; ++i) {
                int row = rowb + i;
                float h  = tanhf(0.125f * ha[i]);
                float hn = (1.f - z[i]) * s1r[l][i] + z[i] * h;
                s1r[l][i] = hn;
                s1q[l][row][colA] = f2q(hn);
                if (l == 1) s1o[row][colA] = hn;
            }
            __syncthreads();
        }

        // ---- score (wave 0): fp32 via s1o; stable until next layer-1 epilogue ----
        if (wave == 0) {
            const int row = l15, c0 = quad * 64;
            float p = 0.f;
#pragma unroll
            for (int u = 0; u < 64; u += 4) {
                float4 sv = *(const float4*)&s1o[row][c0 + u];
                float4 wv = *(const float4*)&wo1s[c0 + u];
                p = fmaf(sv.x, wv.x, p); p = fmaf(sv.y, wv.y, p);
                p = fmaf(sv.z, wv.z, p); p = fmaf(sv.w, wv.w, p);
            }
            p += __shfl_xor(p, 16);
            p += __shfl_xor(p, 32);
            if (lane < 16 && t < lenr) {
                float sc = sigf(p);
                float d = labr - sc;
                accl = fmaf(d, d, accl);
            }
        }
    }

    if (wave == 0) {
        accl += __shfl_xor(accl, 1);
        accl += __shfl_xor(accl, 2);
        accl += __shfl_xor(accl, 4);
        accl += __shfl_xor(accl, 8);
        if (lane == 0) atomicAdd(out, accl);
    }
}

extern "C" void kernel_launch(void* const* d_in, const int* in_sizes, int n_in,
                              void* d_out, int out_size, void* d_ws, size_t ws_size,
                              hipStream_t stream) {
    const float* x    = (const float*)d_in[0];
    const int*   xlen = (const int*)d_in[1];
    const float* xlab = (const float*)d_in[2];
    const float* Wz   = (const float*)d_in[3];
    const float* Uz   = (const float*)d_in[4];
    const float* Wr   = (const float*)d_in[5];
    const float* Ur   = (const float*)d_in[6];
    const float* Wh   = (const float*)d_in[7];
    const float* Uh   = (const float*)d_in[8];
    const float* Wo   = (const float*)d_in[9];
    float* out = (float*)d_out;
    unsigned short* wp16 = (unsigned short*)d_ws;  // 768 KB packed fp8 weights

    // ws is re-poisoned before every timed call -> rebuild packed weights every call.
    prep_weights<<<1536, 256, 0, stream>>>(Wz, Wr, Uz, Ur, Wh, Uh, wp16, out);
    gru_main<<<NWG, 1024, 0, stream>>>(x, xlen, xlab, (const unsigned char*)wp16, Wo, out);
}

// Round 7
// 8434.870 us; speedup vs baseline: 1.0487x; 1.0487x over previous
//
#include <hip/hip_runtime.h>

// Dims fixed by the reference
#define LAY 2
#define BATCH 64
#define TMAX 512
#define DIM 256
#define ROWS 16            // batch rows per workgroup
#define NWG  (BATCH / ROWS)
#define SLAB 65536         // BYTES per packed fp8 matrix (256x256)
#define AST  264           // LDS activation row stride (bytes, fp8)

typedef float floatx4 __attribute__((ext_vector_type(4)));
typedef long  longx2  __attribute__((ext_vector_type(2)));
#define MFMA_FP8 __builtin_amdgcn_mfma_f32_16x16x32_fp8_fp8

__device__ __forceinline__ unsigned int pk2(float a, float b) {
    return (unsigned int)__builtin_amdgcn_cvt_pk_fp8_f32(a, b, 0, false);  // OCP e4m3 x2
}
__device__ __forceinline__ unsigned char f2q(float a) { return (unsigned char)(pk2(a, a) & 0xff); }
__device__ __forceinline__ float sigf(float x) { return 1.f / (1.f + __expf(-x)); }

// ---------------------------------------------------------------------------
// Weight prep (identical to R5/R6): fp32 [L][256][256] ([k][n]) -> e4m3 (x8)
//   byte addr = ((mat*16+nt)*4 + kp)*1024 + lane*16 + half*8 + j
//   holds 8*W[l][ k=(2kp+half)*32 + (lane>>4)*8 + j ][ n=nt*16 + (lane&15) ]
// ---------------------------------------------------------------------------
__global__ void prep_weights(const float* __restrict__ Wz, const float* __restrict__ Wr,
                             const float* __restrict__ Uz, const float* __restrict__ Ur,
                             const float* __restrict__ Wh, const float* __restrict__ Uh,
                             unsigned short* __restrict__ wp, float* __restrict__ out) {
    int t = blockIdx.x * 256 + threadIdx.x;  // N = 393216
    if (t == 0) out[0] = 0.f;
    int e    = t & 3;
    int half = (t >> 2) & 1;
    int lane = (t >> 3) & 63;
    int kp   = (t >> 9) & 3;
    int nt   = (t >> 11) & 15;
    int mat  = t >> 15;          // l*6 + m
    int m = mat % 6;
    int l = mat / 6;
    const float* src;
    switch (m) {                 // 0=Wz 1=Wr 2=Uz 3=Ur 4=Wh 5=Uh
        case 0: src = Wz; break;
        case 1: src = Wr; break;
        case 2: src = Uz; break;
        case 3: src = Ur; break;
        case 4: src = Wh; break;
        default: src = Uh; break;
    }
    int n  = nt * 16 + (lane & 15);
    int k0 = (2 * kp + half) * 32 + (lane >> 4) * 8 + 2 * e;
    float w0 = src[(l << 16) + (k0 << 8) + n] * 8.f;
    float w1 = src[(l << 16) + ((k0 + 1) << 8) + n] * 8.f;
    wp[t] = (unsigned short)(pk2(w0, w1) & 0xffff);
}

// ---- async global->LDS DMA (no VGPR round-trip; compiler cannot sink it) ----
__device__ __forceinline__ void async16(void* lds, const void* g) {
    __builtin_amdgcn_global_load_lds(
        (const __attribute__((address_space(1))) unsigned int*)g,
        (__attribute__((address_space(3))) unsigned int*)lds, 16, 0, 0);
}
// one half-tile = 2KB = two 1KB DMA instrs (LDS dest = uniform base + lane*16)
__device__ __forceinline__ void dmahalf(unsigned char* slot, const unsigned char* g, int lane) {
    async16(slot,        g + lane * 16);
    async16(slot + 1024, g + 1024 + lane * 16);
}
template <int W> __device__ __forceinline__ void waitv() {
    if constexpr (W == 4)      asm volatile("s_waitcnt vmcnt(4)" ::: "memory");
    else if constexpr (W == 2) asm volatile("s_waitcnt vmcnt(2)" ::: "memory");
    else                       asm volatile("s_waitcnt vmcnt(0)" ::: "memory");
}
// consume one staged half-tile: 2 x ds_read_b128 + 4 MFMA (K-order = R5/R6)
__device__ __forceinline__ void halfmm(const unsigned char* slot, int lane,
                                       const long* __restrict__ Af, int kb, floatx4& acc) {
    longx2 c0 = *(const longx2*)(slot + lane * 16);
    longx2 c1 = *(const longx2*)(slot + 1024 + lane * 16);
    acc = MFMA_FP8(Af[2 * kb],     c0.x, acc, 0, 0, 0);
    acc = MFMA_FP8(Af[2 * kb + 1], c0.y, acc, 0, 0, 0);
    acc = MFMA_FP8(Af[2 * kb + 2], c1.x, acc, 0, 0, 0);
    acc = MFMA_FP8(Af[2 * kb + 3], c1.y, acc, 0, 0, 0);
}

// 4 WGs x 16 rows, 16 waves; wave w owns 16-col tile nt=w AND batch row w's x.
// Weight stream: 12 half-tiles/layer through a 3-slot LDS ring, paced by
// explicit vmcnt waits; 3 halves (6 DMA instrs) in flight.
__global__ __launch_bounds__(1024, 4) void gru_main(const float* __restrict__ x,
                                                    const int* __restrict__ xlen,
                                                    const float* __restrict__ xlab,
                                                    const unsigned char* __restrict__ wp,
                                                    const float* __restrict__ Wo,
                                                    float* __restrict__ out) {
    __shared__ __align__(16) unsigned char stage[16][3][2048];   // 96 KB DMA ring
    __shared__ __align__(16) unsigned char s1q[LAY][ROWS][AST];  // S1 (fp8)
    __shared__ __align__(16) unsigned char xq[ROWS][AST];        // x_t (fp8, single buf)
    __shared__ __align__(16) unsigned char rsq[ROWS][AST];       // r*S1 (fp8)
    __shared__ __align__(16) float s1o[ROWS][264];               // layer-1 S1 fp32 (score)
    __shared__ float wo1s[DIM];

    const int tid  = threadIdx.x;
    const int wave = tid >> 6;
    const int lane = tid & 63;
    const int l15  = lane & 15;
    const int quad = lane >> 4;
    const int b0   = blockIdx.x * ROWS;

    // ---- init ----
    for (int i = tid; i < LAY * ROWS * AST; i += 1024) ((unsigned char*)s1q)[i] = 0;
    if (tid < DIM) wo1s[tid] = Wo[2 * tid + 1];
    {   // x_0 -> xq; wave w owns batch row w
        float4 xv = *(const float4*)&x[((size_t)(b0 + wave) * TMAX + 0) * DIM + lane * 4];
        unsigned int u = pk2(xv.x, xv.y) | (pk2(xv.z, xv.w) << 16);
        *(unsigned int*)&xq[wave][lane * 4] = u;
    }
    const int   lenr = xlen[b0 + l15];
    const float labr = xlab[b0 + l15];
    int v = lenr;
#pragma unroll
    for (int o = 1; o < 16; o <<= 1) v = max(v, __shfl_xor(v, o));
    const int tmax = __builtin_amdgcn_readfirstlane(v);

    const int nt   = wave;
    const int colA = nt * 16 + l15;
    const int rowb = quad * 4;
    unsigned char* sA = &stage[wave][0][0];
    unsigned char* sB = &stage[wave][1][0];
    unsigned char* sC = &stage[wave][2][0];
    float s1r[LAY][4];
#pragma unroll
    for (int l = 0; l < LAY; ++l)
#pragma unroll
        for (int i = 0; i < 4; ++i) s1r[l][i] = 0.f;
    float accl = 0.f;
    __syncthreads();

    for (int t = 0; t < tmax; ++t) {
        for (int l = 0; l < LAY; ++l) {
            const unsigned char* Xs = (l == 0) ? &xq[0][0] : &s1q[0][0][0];
            const unsigned char* Ss = &s1q[l][0][0];
            const unsigned char* wl = wp + (size_t)l * 6 * SLAB;
            // matrix order: Wz(0) Uz(2) Wr(1) Ur(3) Wh(4) Uh(5)
            const unsigned char* w0 = wl + 0 * SLAB + nt * 4096;  // Wz
            const unsigned char* w1 = wl + 2 * SLAB + nt * 4096;  // Uz
            const unsigned char* w2 = wl + 1 * SLAB + nt * 4096;  // Wr
            const unsigned char* w3 = wl + 3 * SLAB + nt * 4096;  // Ur
            const unsigned char* w4 = wl + 4 * SLAB + nt * 4096;  // Wh
            const unsigned char* w5 = wl + 5 * SLAB + nt * 4096;  // Uh

            // ---- DMA prologue: 3 halves in flight ----
            dmahalf(sA, w0, lane);          // H0  Wz kp0-1
            dmahalf(sB, w0 + 2048, lane);   // H1  Wz kp2-3
            dmahalf(sC, w1, lane);          // H2  Uz kp0-1

            // x_{t+1} prefetch rides the vmcnt FIFO (1 op; counts stay safe)
            float4 xv;
            const bool pf = (l == 0) && (t + 1 < tmax);
            if (pf) xv = *(const float4*)&x[((size_t)(b0 + wave) * TMAX + (t + 1)) * DIM + lane * 4];

            // A-fragments (held in regs across the layer)
            long xf[8], sf[8];
#pragma unroll
            for (int k = 0; k < 8; ++k) {
                xf[k] = *(const long*)&Xs[l15 * AST + k * 32 + quad * 8];
                sf[k] = *(const long*)&Ss[l15 * AST + k * 32 + quad * 8];
            }

            floatx4 za = {0.f, 0.f, 0.f, 0.f}, ra = za, ha = za;
            // ---- phase 1: stream H0..H9 (z, r, Wh·X), issuing H+3 each step ----
            waitv<4>(); halfmm(sA, lane, xf, 0, za); dmahalf(sA, w1 + 2048, lane);  // H3 Uz b
            waitv<4>(); halfmm(sB, lane, xf, 2, za); dmahalf(sB, w2, lane);         // H4 Wr a
            waitv<4>(); halfmm(sC, lane, sf, 0, za); dmahalf(sC, w2 + 2048, lane);  // H5 Wr b
            waitv<4>(); halfmm(sA, lane, sf, 2, za); dmahalf(sA, w3, lane);         // H6 Ur a
            waitv<4>(); halfmm(sB, lane, xf, 0, ra); dmahalf(sB, w3 + 2048, lane);  // H7 Ur b
            waitv<4>(); halfmm(sC, lane, xf, 2, ra); dmahalf(sC, w4, lane);         // H8 Wh a
            waitv<4>(); halfmm(sA, lane, sf, 0, ra); dmahalf(sA, w4 + 2048, lane);  // H9 Wh b
            waitv<4>(); halfmm(sB, lane, sf, 2, ra); dmahalf(sB, w5, lane);         // H10 Uh a
            waitv<4>(); halfmm(sC, lane, xf, 0, ha); dmahalf(sC, w5 + 2048, lane);  // H11 Uh b
            waitv<4>(); halfmm(sA, lane, xf, 2, ha);

            float z[4];
#pragma unroll
            for (int i = 0; i < 4; ++i) {
                z[i] = sigf(0.125f * za[i]);
                rsq[rowb + i][colA] = f2q(sigf(0.125f * ra[i]) * s1r[l][i]);
            }
            __syncthreads();

            // ---- phase 2: + (r*S) @ Uh ----
            long rf[8];
#pragma unroll
            for (int k = 0; k < 8; ++k)
                rf[k] = *(const long*)&rsq[0][l15 * AST + k * 32 + quad * 8];
            if (pf) {  // publish x_{t+1}: all xf reads of this step happened pre-barrier
                unsigned int u = pk2(xv.x, xv.y) | (pk2(xv.z, xv.w) << 16);
                *(unsigned int*)&xq[wave][lane * 4] = u;
            }
            waitv<2>(); halfmm(sB, lane, rf, 0, ha);
            waitv<0>(); halfmm(sC, lane, rf, 2, ha);

#pragma unroll
            for (int i = 0; i < 4; ++i) {
                int row = rowb + i;
                float h  = tanhf(0.125f * ha[i]);
                float hn = (1.f - z[i]) * s1r[l][i] + z[i] * h;
                s1r[l][i] = hn;
                s1q[l][row][colA] = f2q(hn);
                if (l == 1) s1o[row][colA] = hn;
            }
            __syncthreads();
        }

        // ---- score (wave 0): fp32 via s1o; stable until next layer-1 epilogue ----
        if (wave == 0) {
            const int row = l15, c0 = quad * 64;
            float p = 0.f;
#pragma unroll
            for (int u = 0; u < 64; u += 4) {
                float4 sv = *(const float4*)&s1o[row][c0 + u];
                float4 wv = *(const float4*)&wo1s[c0 + u];
                p = fmaf(sv.x, wv.x, p); p = fmaf(sv.y, wv.y, p);
                p = fmaf(sv.z, wv.z, p); p = fmaf(sv.w, wv.w, p);
            }
            p += __shfl_xor(p, 16);
            p += __shfl_xor(p, 32);
            if (lane < 16 && t < lenr) {
                float sc = sigf(p);
                float d = labr - sc;
                accl = fmaf(d, d, accl);
            }
        }
    }

    if (wave == 0) {
        accl += __shfl_xor(accl, 1);
        accl += __shfl_xor(accl, 2);
        accl += __shfl_xor(accl, 4);
        accl += __shfl_xor(accl, 8);
        if (lane == 0) atomicAdd(out, accl);
    }
}

extern "C" void kernel_launch(void* const* d_in, const int* in_sizes, int n_in,
                              void* d_out, int out_size, void* d_ws, size_t ws_size,
                              hipStream_t stream) {
    const float* x    = (const float*)d_in[0];
    const int*   xlen = (const int*)d_in[1];
    const float* xlab = (const float*)d_in[2];
    const float* Wz   = (const float*)d_in[3];
    const float* Uz   = (const float*)d_in[4];
    const float* Wr   = (const float*)d_in[5];
    const float* Ur   = (const float*)d_in[6];
    const float* Wh   = (const float*)d_in[7];
    const float* Uh   = (const float*)d_in[8];
    const float* Wo   = (const float*)d_in[9];
    float* out = (float*)d_out;
    unsigned short* wp16 = (unsigned short*)d_ws;  // 768 KB packed fp8 weights

    // ws is re-poisoned before every timed call -> rebuild packed weights every call.
    prep_weights<<<1536, 256, 0, stream>>>(Wz, Wr, Uz, Ur, Wh, Uh, wp16, out);
    gru_main<<<NWG, 1024, 0, stream>>>(x, xlen, xlab, (const unsigned char*)wp16, Wo, out);
}

// Round 8
// 3373.963 us; speedup vs baseline: 2.6218x; 2.5000x over previous
//
#include <hip/hip_runtime.h>

// Dims fixed by the reference
#define LAY 2
#define BATCH 64
#define TMAX 512
#define DIM 256
#define AST 264   // LDS activation row stride (bytes, fp8)

typedef float floatx4 __attribute__((ext_vector_type(4)));
typedef __bf16 bf16x8 __attribute__((ext_vector_type(8)));
#define MFMA_FP8  __builtin_amdgcn_mfma_f32_16x16x32_fp8_fp8
#define MFMA_BF16 __builtin_amdgcn_mfma_f32_16x16x32_bf16

// d_ws layout (requires ws >= ~74 MB)
#define OFF_WPW 0x60000     // bf16 B-frag W-mats, 6 x 128 KB
#define OFF_XP  0x200000    // layer-0 X-projections fp8, 25.2 MB
#define OFF_HP  0x1C00000   // layer-1 input projections fp8, 25.2 MB
#define OFF_HN  0x3600000   // hn0 bf16 [b*512+t][256], 16.8 MB

__device__ __forceinline__ unsigned short f2bf(float f) {
    unsigned int u = __float_as_uint(f);
    unsigned int r = u + 0x7fffu + ((u >> 16) & 1u);  // RNE
    return (unsigned short)(r >> 16);
}
__device__ __forceinline__ unsigned int pk2(float a, float b) {
    return (unsigned int)__builtin_amdgcn_cvt_pk_fp8_f32(a, b, 0, false);  // OCP e4m3 x2
}
__device__ __forceinline__ unsigned char f2q(float a) { return (unsigned char)(pk2(a, a) & 0xff); }
__device__ __forceinline__ void unp4(unsigned int u, float* f) {
    auto lo = __builtin_amdgcn_cvt_pk_f32_fp8((int)u, false);
    auto hi = __builtin_amdgcn_cvt_pk_f32_fp8((int)u, true);
    f[0] = lo[0]; f[1] = lo[1]; f[2] = hi[0]; f[3] = hi[1];
}
__device__ __forceinline__ float sigf(float x) { return 1.f / (1.f + __expf(-x)); }

// ---------------------------------------------------------------------------
// Weight prep. Two packings:
//  U-mats (Uz,Ur,Uh x 2 layers) fp8 e4m3 x8 in R5-proven layout (mu=l*3+g):
//    byte ((mu*16+nt)*4+kp)*1024 + lane*16 + half*8 + j ->
//      8*U[k=(2kp+half)*32+(lane>>4)*8+j][n=nt*16+(lane&15)]
//  W-mats (Wz,Wr,Wh x 2 layers) bf16 B-frags in R4-proven layout (mw=l*3+g):
//    byte ((mw*16+nt)*8+kf)*1024 + lane*16 + 2j ->
//      bf16 W[k=kf*32+(lane>>4)*8+j][n=nt*16+(lane&15)]
// Also zeroes d_out.
// ---------------------------------------------------------------------------
__global__ void prep_weights(const float* __restrict__ Wz, const float* __restrict__ Wr,
                             const float* __restrict__ Wh, const float* __restrict__ Uz,
                             const float* __restrict__ Ur, const float* __restrict__ Uh,
                             unsigned char* __restrict__ ws, float* __restrict__ out) {
    int T = blockIdx.x * 256 + threadIdx.x;  // 1536*256 = 393216
    if (T == 0) out[0] = 0.f;
    if (T < 196608) {  // U-mats, fp8
        int e = T & 3, half = (T >> 2) & 1, lane = (T >> 3) & 63;
        int kp = (T >> 9) & 3, nt = (T >> 11) & 15, mu = T >> 15;
        int g = mu % 3, l = mu / 3;
        const float* s = (g == 0 ? Uz : g == 1 ? Ur : Uh) + l * 65536;
        int n  = nt * 16 + (lane & 15);
        int k0 = (2 * kp + half) * 32 + (lane >> 4) * 8 + 2 * e;
        float w0 = s[(k0 << 8) + n] * 8.f;        // x8: dodge e4m3 denormals
        float w1 = s[((k0 + 1) << 8) + n] * 8.f;  // undone by 0.125 post-acc
        int addr = ((mu * 16 + nt) * 4 + kp) * 1024 + lane * 16 + half * 8 + 2 * e;
        *(unsigned short*)(ws + addr) = (unsigned short)(pk2(w0, w1) & 0xffff);
    } else {           // W-mats, bf16
        int T2 = T - 196608;
        int e = T2 & 3, lane = (T2 >> 2) & 63;
        int kf = (T2 >> 8) & 7, nt = (T2 >> 11) & 15, mw = T2 >> 15;
        int g = mw % 3, l = mw / 3;
        const float* s = (g == 0 ? Wz : g == 1 ? Wr : Wh) + l * 65536;
        int n  = nt * 16 + (lane & 15);
        int k0 = kf * 32 + (lane >> 4) * 8 + 2 * e;
        unsigned int v = (unsigned int)f2bf(s[(k0 << 8) + n]) |
                         ((unsigned int)f2bf(s[((k0 + 1) << 8) + n]) << 16);
        int addr = ((mw * 16 + nt) * 8 + kf) * 1024 + lane * 16 + 4 * e;
        *(unsigned int*)(ws + OFF_WPW + addr) = v;
    }
}

// ---------------------------------------------------------------------------
// Projection GEMM (phases A and C): rows = 16 batch rows at fixed t,
// cols = 3 mats x 256. Grid 2048 = bg*512+t. 16 waves; wave w = col tile w of
// each mat. Output fp8(x16) in lane-natural C-frag order:
//   xp[u32: (bgt*48 + g*16 + w)*64 + lane] = e4m3(16*acc[0..3])
// ---------------------------------------------------------------------------
template <int F32SRC>
__global__ __launch_bounds__(1024) void proj_kernel(const void* __restrict__ src,
                                                    const unsigned char* __restrict__ wpW,
                                                    unsigned int* __restrict__ xpo, int matbase) {
    const int bgt = blockIdx.x;
    const int t = bgt & 511, bg = bgt >> 9;
    const int tid = threadIdx.x, wave = tid >> 6, lane = tid & 63;
    const int l15 = lane & 15, quad = lane >> 4;
    const size_t rowoff = ((size_t)(bg * 16 + l15) * 512 + t) * 256;

    bf16x8 af[8];
    if (F32SRC) {
        const float* s = (const float*)src + rowoff;
#pragma unroll
        for (int kf = 0; kf < 8; ++kf) {
            float4 a = *(const float4*)(s + kf * 32 + quad * 8);
            float4 b = *(const float4*)(s + kf * 32 + quad * 8 + 4);
            union { unsigned short u[8]; bf16x8 v; } cv;
            cv.u[0] = f2bf(a.x); cv.u[1] = f2bf(a.y); cv.u[2] = f2bf(a.z); cv.u[3] = f2bf(a.w);
            cv.u[4] = f2bf(b.x); cv.u[5] = f2bf(b.y); cv.u[6] = f2bf(b.z); cv.u[7] = f2bf(b.w);
            af[kf] = cv.v;
        }
    } else {
        const unsigned short* s = (const unsigned short*)src + rowoff;
#pragma unroll
        for (int kf = 0; kf < 8; ++kf) af[kf] = *(const bf16x8*)(s + kf * 32 + quad * 8);
    }

    floatx4 az = {0.f, 0.f, 0.f, 0.f}, ar = az, ah = az;
    const unsigned char* bz = wpW + (size_t)(((matbase + 0) * 16 + wave) * 8) * 1024 + lane * 16;
    const unsigned char* br = wpW + (size_t)(((matbase + 1) * 16 + wave) * 8) * 1024 + lane * 16;
    const unsigned char* bh = wpW + (size_t)(((matbase + 2) * 16 + wave) * 8) * 1024 + lane * 16;
#pragma unroll
    for (int kf = 0; kf < 8; ++kf) {
        az = MFMA_BF16(af[kf], *(const bf16x8*)(bz + kf * 1024), az, 0, 0, 0);
        ar = MFMA_BF16(af[kf], *(const bf16x8*)(br + kf * 1024), ar, 0, 0, 0);
        ah = MFMA_BF16(af[kf], *(const bf16x8*)(bh + kf * 1024), ah, 0, 0, 0);
    }
    const size_t ob = (size_t)bgt * 3072 + wave * 64 + lane;
    xpo[ob]        = pk2(16.f * az[0], 16.f * az[1]) | (pk2(16.f * az[2], 16.f * az[3]) << 16);
    xpo[ob + 1024] = pk2(16.f * ar[0], 16.f * ar[1]) | (pk2(16.f * ar[2], 16.f * ar[3]) << 16);
    xpo[ob + 2048] = pk2(16.f * ah[0], 16.f * ah[1]) | (pk2(16.f * ah[2], 16.f * ah[3]) << 16);
}

// ---------------------------------------------------------------------------
// Recurrence (phases B and D): 4 WGs x 16 rows, 8 waves; wave w owns col
// tiles 2w, 2w+1. U-weights REGISTER-RESIDENT (48 longs/lane) -> zero weight
// traffic per step. XP/HP additive projections read per step (coalesced u32).
// B (SCORE=0) emits hn0 bf16; D (SCORE=1) computes the masked loss.
// ---------------------------------------------------------------------------
template <int SCORE>
__global__ __launch_bounds__(512, 2) void recur_kernel(const unsigned int* __restrict__ xp,
                                                       const unsigned char* __restrict__ wpU,
                                                       int lbase,
                                                       unsigned short* __restrict__ hnout,
                                                       const int* __restrict__ xlen,
                                                       const float* __restrict__ xlab,
                                                       const float* __restrict__ Wo,
                                                       float* __restrict__ out) {
    __shared__ __align__(16) unsigned char s1q[16][AST];
    __shared__ __align__(16) unsigned char rsq[16][AST];
    __shared__ __align__(16) float s1o[16][264];
    __shared__ float wo1s[DIM];

    const int tid = threadIdx.x, wave = tid >> 6, lane = tid & 63;
    const int l15 = lane & 15, quad = lane >> 4;
    const int bg = blockIdx.x, b0 = bg * 16;

    for (int i = tid; i < 16 * AST; i += 512) ((unsigned char*)s1q)[i] = 0;
    if (SCORE && tid < DIM) wo1s[tid] = Wo[2 * tid + 1];
    const int lenr = xlen[b0 + l15];
    const float labr = SCORE ? xlab[b0 + l15] : 0.f;
    int v = lenr;
#pragma unroll
    for (int o = 1; o < 16; o <<= 1) v = max(v, __shfl_xor(v, o));
    const int tmax = __builtin_amdgcn_readfirstlane(v);

    const int nt0 = 2 * wave, nt1 = nt0 + 1;
    const int colA = nt0 * 16 + l15, colB = colA + 16, rowb = quad * 4;

    long uz[2][8], ur[2][8], uh[2][8];
#pragma unroll
    for (int c = 0; c < 2; ++c) {
        int nt = nt0 + c;
        const unsigned char* pz = wpU + (size_t)(((lbase + 0) * 16 + nt) * 4) * 1024 + lane * 16;
        const unsigned char* pr = wpU + (size_t)(((lbase + 1) * 16 + nt) * 4) * 1024 + lane * 16;
        const unsigned char* ph = wpU + (size_t)(((lbase + 2) * 16 + nt) * 4) * 1024 + lane * 16;
#pragma unroll
        for (int kf = 0; kf < 8; ++kf) {
            int o = (kf >> 1) * 1024 + (kf & 1) * 8;
            uz[c][kf] = *(const long*)(pz + o);
            ur[c][kf] = *(const long*)(pr + o);
            uh[c][kf] = *(const long*)(ph + o);
        }
    }
    float s1r[2][4] = {};
    float accl = 0.f;
    __syncthreads();

    for (int t = 0; t < tmax; ++t) {
        const unsigned int* xpt = xp + (size_t)(bg * 512 + t) * 3072 + lane;
        unsigned int xz0 = xpt[nt0 * 64],        xz1 = xpt[nt1 * 64];
        unsigned int xr0 = xpt[1024 + nt0 * 64], xr1 = xpt[1024 + nt1 * 64];
        unsigned int xh0 = xpt[2048 + nt0 * 64], xh1 = xpt[2048 + nt1 * 64];

        // ---- phase 1: z, r ----
        long sf[8];
#pragma unroll
        for (int kf = 0; kf < 8; ++kf) sf[kf] = *(const long*)&s1q[l15][kf * 32 + quad * 8];
        floatx4 za = {0.f, 0.f, 0.f, 0.f}, zb = za, ra = za, rb = za;
#pragma unroll
        for (int kf = 0; kf < 8; ++kf) {
            za = MFMA_FP8(sf[kf], uz[0][kf], za, 0, 0, 0);
            zb = MFMA_FP8(sf[kf], uz[1][kf], zb, 0, 0, 0);
            ra = MFMA_FP8(sf[kf], ur[0][kf], ra, 0, 0, 0);
            rb = MFMA_FP8(sf[kf], ur[1][kf], rb, 0, 0, 0);
        }
        float xzf0[4], xzf1[4], xrf0[4], xrf1[4];
        unp4(xz0, xzf0); unp4(xz1, xzf1); unp4(xr0, xrf0); unp4(xr1, xrf1);
        float z0[4], z1[4];
#pragma unroll
        for (int i = 0; i < 4; ++i) {
            z0[i] = sigf(0.125f * za[i] + 0.0625f * xzf0[i]);
            z1[i] = sigf(0.125f * zb[i] + 0.0625f * xzf1[i]);
            float r0 = sigf(0.125f * ra[i] + 0.0625f * xrf0[i]);
            float r1 = sigf(0.125f * rb[i] + 0.0625f * xrf1[i]);
            rsq[rowb + i][colA] = f2q(r0 * s1r[0][i]);
            rsq[rowb + i][colB] = f2q(r1 * s1r[1][i]);
        }
        __syncthreads();

        // ---- phase 2: h, hn ----
        long rf[8];
#pragma unroll
        for (int kf = 0; kf < 8; ++kf) rf[kf] = *(const long*)&rsq[l15][kf * 32 + quad * 8];
        floatx4 ha = {0.f, 0.f, 0.f, 0.f}, hb = ha;
#pragma unroll
        for (int kf = 0; kf < 8; ++kf) {
            ha = MFMA_FP8(rf[kf], uh[0][kf], ha, 0, 0, 0);
            hb = MFMA_FP8(rf[kf], uh[1][kf], hb, 0, 0, 0);
        }
        float xhf0[4], xhf1[4];
        unp4(xh0, xhf0); unp4(xh1, xhf1);
#pragma unroll
        for (int i = 0; i < 4; ++i) {
            float h0 = tanhf(0.125f * ha[i] + 0.0625f * xhf0[i]);
            float h1 = tanhf(0.125f * hb[i] + 0.0625f * xhf1[i]);
            float hnA = (1.f - z0[i]) * s1r[0][i] + z0[i] * h0;
            float hnB = (1.f - z1[i]) * s1r[1][i] + z1[i] * h1;
            s1r[0][i] = hnA; s1r[1][i] = hnB;
            s1q[rowb + i][colA] = f2q(hnA); s1q[rowb + i][colB] = f2q(hnB);
            s1o[rowb + i][colA] = hnA;      s1o[rowb + i][colB] = hnB;
        }
        __syncthreads();

        if (!SCORE) {
            // cooperative hn0 write (coalesced); next s1o write is 1 barrier away
            const int r = tid >> 5, c = (tid & 31) * 8;
            float4 f0 = *(const float4*)&s1o[r][c];
            float4 f1 = *(const float4*)&s1o[r][c + 4];
            uint4 o4;
            o4.x = f2bf(f0.x) | ((unsigned)f2bf(f0.y) << 16);
            o4.y = f2bf(f0.z) | ((unsigned)f2bf(f0.w) << 16);
            o4.z = f2bf(f1.x) | ((unsigned)f2bf(f1.y) << 16);
            o4.w = f2bf(f1.z) | ((unsigned)f2bf(f1.w) << 16);
            *(uint4*)(hnout + ((size_t)(b0 + r) * 512 + t) * 256 + c) = o4;
        } else if (wave == 0) {
            const int row = l15, c0 = quad * 64;
            float p = 0.f;
#pragma unroll
            for (int u = 0; u < 64; u += 4) {
                float4 sv = *(const float4*)&s1o[row][c0 + u];
                float4 wv = *(const float4*)&wo1s[c0 + u];
                p = fmaf(sv.x, wv.x, p); p = fmaf(sv.y, wv.y, p);
                p = fmaf(sv.z, wv.z, p); p = fmaf(sv.w, wv.w, p);
            }
            p += __shfl_xor(p, 16);
            p += __shfl_xor(p, 32);
            if (lane < 16 && t < lenr) {
                float sc = sigf(p);
                float d = labr - sc;
                accl = fmaf(d, d, accl);
            }
        }
    }

    if (SCORE && wave == 0) {
        accl += __shfl_xor(accl, 1);
        accl += __shfl_xor(accl, 2);
        accl += __shfl_xor(accl, 4);
        accl += __shfl_xor(accl, 8);
        if (lane == 0) atomicAdd(out, accl);
    }
}

extern "C" void kernel_launch(void* const* d_in, const int* in_sizes, int n_in,
                              void* d_out, int out_size, void* d_ws, size_t ws_size,
                              hipStream_t stream) {
    const float* x    = (const float*)d_in[0];
    const int*   xlen = (const int*)d_in[1];
    const float* xlab = (const float*)d_in[2];
    const float* Wz   = (const float*)d_in[3];
    const float* Uz   = (const float*)d_in[4];
    const float* Wr   = (const float*)d_in[5];
    const float* Ur   = (const float*)d_in[6];
    const float* Wh   = (const float*)d_in[7];
    const float* Uh   = (const float*)d_in[8];
    const float* Wo   = (const float*)d_in[9];
    float* out = (float*)d_out;

    unsigned char* ws  = (unsigned char*)d_ws;
    unsigned char* wpU = ws;                                 // fp8 U-frags, 384 KB
    unsigned char* wpW = ws + OFF_WPW;                       // bf16 W-frags, 768 KB
    unsigned int*  XP  = (unsigned int*)(ws + OFF_XP);       // 25.2 MB
    unsigned int*  HP  = (unsigned int*)(ws + OFF_HP);       // 25.2 MB
    unsigned short* HN = (unsigned short*)(ws + OFF_HN);     // 16.8 MB

    // ws re-poisoned every call -> rebuild everything each time.
    prep_weights<<<1536, 256, 0, stream>>>(Wz, Wr, Wh, Uz, Ur, Uh, ws, out);
    proj_kernel<1><<<2048, 1024, 0, stream>>>(x, wpW, XP, 0);                       // A: x @ W(l0)
    recur_kernel<0><<<4, 512, 0, stream>>>(XP, wpU, 0, HN, xlen, xlab, Wo, out);    // B: layer-0 scan
    proj_kernel<0><<<2048, 1024, 0, stream>>>(HN, wpW, HP, 3);                      // C: hn0 @ W(l1)
    recur_kernel<1><<<4, 512, 0, stream>>>(HP, wpU, 3, nullptr, xlen, xlab, Wo, out); // D: layer-1 + loss
}

// Round 9
// 2729.668 us; speedup vs baseline: 3.2406x; 1.2360x over previous
//
#include <hip/hip_runtime.h>

// Dims fixed by the reference
#define LAY 2
#define BATCH 64
#define TMAX 512
#define DIM 256
#define AST 264   // LDS activation row stride (bytes, fp8)

typedef float floatx4 __attribute__((ext_vector_type(4)));
typedef __bf16 bf16x8 __attribute__((ext_vector_type(8)));
#define MFMA_FP8  __builtin_amdgcn_mfma_f32_16x16x32_fp8_fp8
#define MFMA_BF16 __builtin_amdgcn_mfma_f32_16x16x32_bf16

// d_ws layout (requires ws >= ~74 MB)
#define OFF_WPW 0x60000     // bf16 B-frag W-mats, 6 x 128 KB
#define OFF_XP  0x200000    // layer-0 X-projections fp8, 25.2 MB
#define OFF_HP  0x1C00000   // layer-1 input projections fp8, 25.2 MB
#define OFF_HN  0x3600000   // hn0 bf16 [b*512+t][256], 16.8 MB

__device__ __forceinline__ unsigned short f2bf(float f) {
    unsigned int u = __float_as_uint(f);
    unsigned int r = u + 0x7fffu + ((u >> 16) & 1u);  // RNE
    return (unsigned short)(r >> 16);
}
__device__ __forceinline__ unsigned int pk2(float a, float b) {
    return (unsigned int)__builtin_amdgcn_cvt_pk_fp8_f32(a, b, 0, false);  // OCP e4m3 x2
}
__device__ __forceinline__ unsigned char f2q(float a) { return (unsigned char)(pk2(a, a) & 0xff); }
__device__ __forceinline__ void unp4(unsigned int u, float* f) {
    auto lo = __builtin_amdgcn_cvt_pk_f32_fp8((int)u, false);
    auto hi = __builtin_amdgcn_cvt_pk_f32_fp8((int)u, true);
    f[0] = lo[0]; f[1] = lo[1]; f[2] = hi[0]; f[3] = hi[1];
}
__device__ __forceinline__ float sigf(float x) { return 1.f / (1.f + __expf(-x)); }
// tanh(y) = 2*sigmoid(2y) - 1  (fast path: v_exp + v_rcp, ~7 instr vs libm ~35)
__device__ __forceinline__ float tanhfast2y(float twoy) { return 2.f * sigf(twoy) - 1.f; }

// ---------------------------------------------------------------------------
// Weight prep (identical to R8). U-mats fp8 e4m3 x8 (mu=l*3+g):
//   byte ((mu*16+nt)*4+kp)*1024 + lane*16 + half*8 + j ->
//     8*U[k=(2kp+half)*32+(lane>>4)*8+j][n=nt*16+(lane&15)]
// W-mats bf16 B-frags (mw=l*3+g):
//   byte ((mw*16+nt)*8+kf)*1024 + lane*16 + 2j ->
//     bf16 W[k=kf*32+(lane>>4)*8+j][n=nt*16+(lane&15)]
// Also zeroes d_out.
// ---------------------------------------------------------------------------
__global__ void prep_weights(const float* __restrict__ Wz, const float* __restrict__ Wr,
                             const float* __restrict__ Wh, const float* __restrict__ Uz,
                             const float* __restrict__ Ur, const float* __restrict__ Uh,
                             unsigned char* __restrict__ ws, float* __restrict__ out) {
    int T = blockIdx.x * 256 + threadIdx.x;  // 1536*256 = 393216
    if (T == 0) out[0] = 0.f;
    if (T < 196608) {  // U-mats, fp8
        int e = T & 3, half = (T >> 2) & 1, lane = (T >> 3) & 63;
        int kp = (T >> 9) & 3, nt = (T >> 11) & 15, mu = T >> 15;
        int g = mu % 3, l = mu / 3;
        const float* s = (g == 0 ? Uz : g == 1 ? Ur : Uh) + l * 65536;
        int n  = nt * 16 + (lane & 15);
        int k0 = (2 * kp + half) * 32 + (lane >> 4) * 8 + 2 * e;
        float w0 = s[(k0 << 8) + n] * 8.f;        // x8: dodge e4m3 denormals
        float w1 = s[((k0 + 1) << 8) + n] * 8.f;  // undone by 0.125 post-acc
        int addr = ((mu * 16 + nt) * 4 + kp) * 1024 + lane * 16 + half * 8 + 2 * e;
        *(unsigned short*)(ws + addr) = (unsigned short)(pk2(w0, w1) & 0xffff);
    } else {           // W-mats, bf16
        int T2 = T - 196608;
        int e = T2 & 3, lane = (T2 >> 2) & 63;
        int kf = (T2 >> 8) & 7, nt = (T2 >> 11) & 15, mw = T2 >> 15;
        int g = mw % 3, l = mw / 3;
        const float* s = (g == 0 ? Wz : g == 1 ? Wr : Wh) + l * 65536;
        int n  = nt * 16 + (lane & 15);
        int k0 = kf * 32 + (lane >> 4) * 8 + 2 * e;
        unsigned int v = (unsigned int)f2bf(s[(k0 << 8) + n]) |
                         ((unsigned int)f2bf(s[((k0 + 1) << 8) + n]) << 16);
        int addr = ((mw * 16 + nt) * 8 + kf) * 1024 + lane * 16 + 4 * e;
        *(unsigned int*)(ws + OFF_WPW + addr) = v;
    }
}

// ---------------------------------------------------------------------------
// Projection GEMM (identical to R8). Grid 2048 = bg*512+t; wave w = col tile.
// Output fp8(x16) lane-natural: xp[(bgt*48 + g*16 + w)*64 + lane]
// ---------------------------------------------------------------------------
template <int F32SRC>
__global__ __launch_bounds__(1024) void proj_kernel(const void* __restrict__ src,
                                                    const unsigned char* __restrict__ wpW,
                                                    unsigned int* __restrict__ xpo, int matbase) {
    const int bgt = blockIdx.x;
    const int t = bgt & 511, bg = bgt >> 9;
    const int tid = threadIdx.x, wave = tid >> 6, lane = tid & 63;
    const int l15 = lane & 15, quad = lane >> 4;
    const size_t rowoff = ((size_t)(bg * 16 + l15) * 512 + t) * 256;

    bf16x8 af[8];
    if (F32SRC) {
        const float* s = (const float*)src + rowoff;
#pragma unroll
        for (int kf = 0; kf < 8; ++kf) {
            float4 a = *(const float4*)(s + kf * 32 + quad * 8);
            float4 b = *(const float4*)(s + kf * 32 + quad * 8 + 4);
            union { unsigned short u[8]; bf16x8 v; } cv;
            cv.u[0] = f2bf(a.x); cv.u[1] = f2bf(a.y); cv.u[2] = f2bf(a.z); cv.u[3] = f2bf(a.w);
            cv.u[4] = f2bf(b.x); cv.u[5] = f2bf(b.y); cv.u[6] = f2bf(b.z); cv.u[7] = f2bf(b.w);
            af[kf] = cv.v;
        }
    } else {
        const unsigned short* s = (const unsigned short*)src + rowoff;
#pragma unroll
        for (int kf = 0; kf < 8; ++kf) af[kf] = *(const bf16x8*)(s + kf * 32 + quad * 8);
    }

    floatx4 az = {0.f, 0.f, 0.f, 0.f}, ar = az, ah = az;
    const unsigned char* bz = wpW + (size_t)(((matbase + 0) * 16 + wave) * 8) * 1024 + lane * 16;
    const unsigned char* br = wpW + (size_t)(((matbase + 1) * 16 + wave) * 8) * 1024 + lane * 16;
    const unsigned char* bh = wpW + (size_t)(((matbase + 2) * 16 + wave) * 8) * 1024 + lane * 16;
#pragma unroll
    for (int kf = 0; kf < 8; ++kf) {
        az = MFMA_BF16(af[kf], *(const bf16x8*)(bz + kf * 1024), az, 0, 0, 0);
        ar = MFMA_BF16(af[kf], *(const bf16x8*)(br + kf * 1024), ar, 0, 0, 0);
        ah = MFMA_BF16(af[kf], *(const bf16x8*)(bh + kf * 1024), ah, 0, 0, 0);
    }
    const size_t ob = (size_t)bgt * 3072 + wave * 64 + lane;
    xpo[ob]        = pk2(16.f * az[0], 16.f * az[1]) | (pk2(16.f * az[2], 16.f * az[3]) << 16);
    xpo[ob + 1024] = pk2(16.f * ar[0], 16.f * ar[1]) | (pk2(16.f * ar[2], 16.f * ar[3]) << 16);
    xpo[ob + 2048] = pk2(16.f * ah[0], 16.f * ah[1]) | (pk2(16.f * ah[2], 16.f * ah[3]) << 16);
}

// ---------------------------------------------------------------------------
// Recurrence: 4 WGs x 16 rows, 16 waves x 1 col-tile (nt = wave). U-weights
// register-resident (24 longs/lane). z-sigmoid deferred to phase 2 (za acc
// crosses the barrier in registers); fast tanh. 2 barriers/step.
// ---------------------------------------------------------------------------
template <int SCORE>
__global__ __launch_bounds__(1024, 4) void recur_kernel(const unsigned int* __restrict__ xp,
                                                        const unsigned char* __restrict__ wpU,
                                                        int lbase,
                                                        unsigned short* __restrict__ hnout,
                                                        const int* __restrict__ xlen,
                                                        const float* __restrict__ xlab,
                                                        const float* __restrict__ Wo,
                                                        float* __restrict__ out) {
    __shared__ __align__(16) unsigned char s1q[16][AST];
    __shared__ __align__(16) unsigned char rsq[16][AST];
    __shared__ __align__(16) float s1o[16][264];
    __shared__ float wo1s[DIM];

    const int tid = threadIdx.x, wave = tid >> 6, lane = tid & 63;
    const int l15 = lane & 15, quad = lane >> 4;
    const int bg = blockIdx.x, b0 = bg * 16;

    for (int i = tid; i < 16 * AST; i += 1024) ((unsigned char*)s1q)[i] = 0;
    if (SCORE && tid < DIM) wo1s[tid] = Wo[2 * tid + 1];
    const int lenr = xlen[b0 + l15];
    const float labr = SCORE ? xlab[b0 + l15] : 0.f;
    int v = lenr;
#pragma unroll
    for (int o = 1; o < 16; o <<= 1) v = max(v, __shfl_xor(v, o));
    const int tmax = __builtin_amdgcn_readfirstlane(v);

    const int nt = wave;
    const int colA = nt * 16 + l15, rowb = quad * 4;

    // register-resident U fragments for this wave's 16-col tile
    long uz[8], ur[8], uh[8];
    {
        const unsigned char* pz = wpU + (size_t)(((lbase + 0) * 16 + nt) * 4) * 1024 + lane * 16;
        const unsigned char* pr = wpU + (size_t)(((lbase + 1) * 16 + nt) * 4) * 1024 + lane * 16;
        const unsigned char* ph = wpU + (size_t)(((lbase + 2) * 16 + nt) * 4) * 1024 + lane * 16;
#pragma unroll
        for (int kf = 0; kf < 8; ++kf) {
            int o = (kf >> 1) * 1024 + (kf & 1) * 8;
            uz[kf] = *(const long*)(pz + o);
            ur[kf] = *(const long*)(pr + o);
            uh[kf] = *(const long*)(ph + o);
        }
    }
    float s1r[4] = {};
    float accl = 0.f;
    __syncthreads();

    for (int t = 0; t < tmax; ++t) {
        const unsigned int* xpt = xp + (size_t)(bg * 512 + t) * 3072 + lane;
        unsigned int xz = xpt[nt * 64];
        unsigned int xr = xpt[1024 + nt * 64];
        unsigned int xh = xpt[2048 + nt * 64];

        // ---- phase 1: r (on the critical path) + z-MFMAs (acc dangles) ----
        long sf[8];
#pragma unroll
        for (int kf = 0; kf < 8; ++kf) sf[kf] = *(const long*)&s1q[l15][kf * 32 + quad * 8];
        floatx4 za = {0.f, 0.f, 0.f, 0.f}, ra = za;
#pragma unroll
        for (int kf = 0; kf < 8; ++kf) {
            ra = MFMA_FP8(sf[kf], ur[kf], ra, 0, 0, 0);
            za = MFMA_FP8(sf[kf], uz[kf], za, 0, 0, 0);
        }
        float xrf[4];
        unp4(xr, xrf);
#pragma unroll
        for (int i = 0; i < 4; ++i) {
            float r = sigf(0.125f * ra[i] + 0.0625f * xrf[i]);
            rsq[rowb + i][colA] = f2q(r * s1r[i]);
        }
        __syncthreads();

        // ---- phase 2: h; z-sigmoid overlaps the Uh MFMA ----
        long rf[8];
#pragma unroll
        for (int kf = 0; kf < 8; ++kf) rf[kf] = *(const long*)&rsq[l15][kf * 32 + quad * 8];
        floatx4 ha = {0.f, 0.f, 0.f, 0.f};
#pragma unroll
        for (int kf = 0; kf < 8; ++kf) ha = MFMA_FP8(rf[kf], uh[kf], ha, 0, 0, 0);
        float xzf[4], xhf[4];
        unp4(xz, xzf); unp4(xh, xhf);
#pragma unroll
        for (int i = 0; i < 4; ++i) {
            float z = sigf(0.125f * za[i] + 0.0625f * xzf[i]);
            float h = tanhfast2y(0.25f * ha[i] + 0.125f * xhf[i]);  // tanh(0.125ha+0.0625xh)
            float hn = (1.f - z) * s1r[i] + z * h;
            s1r[i] = hn;
            s1q[rowb + i][colA] = f2q(hn);
            s1o[rowb + i][colA] = hn;
        }
        __syncthreads();

        if (!SCORE) {
            // cooperative hn0 write: row=tid>>6, 4 cols/thread; coalesced 8B stores
            const int r = tid >> 6, c = (tid & 63) * 4;
            float4 f0 = *(const float4*)&s1o[r][c];
            uint2 o2;
            o2.x = f2bf(f0.x) | ((unsigned)f2bf(f0.y) << 16);
            o2.y = f2bf(f0.z) | ((unsigned)f2bf(f0.w) << 16);
            *(uint2*)(hnout + ((size_t)(b0 + r) * 512 + t) * 256 + c) = o2;
        } else if (wave == 0) {
            const int row = l15, c0 = quad * 64;
            float p = 0.f;
#pragma unroll
            for (int u = 0; u < 64; u += 4) {
                float4 sv = *(const float4*)&s1o[row][c0 + u];
                float4 wv = *(const float4*)&wo1s[c0 + u];
                p = fmaf(sv.x, wv.x, p); p = fmaf(sv.y, wv.y, p);
                p = fmaf(sv.z, wv.z, p); p = fmaf(sv.w, wv.w, p);
            }
            p += __shfl_xor(p, 16);
            p += __shfl_xor(p, 32);
            if (lane < 16 && t < lenr) {
                float sc = sigf(p);
                float d = labr - sc;
                accl = fmaf(d, d, accl);
            }
        }
    }

    if (SCORE && wave == 0) {
        accl += __shfl_xor(accl, 1);
        accl += __shfl_xor(accl, 2);
        accl += __shfl_xor(accl, 4);
        accl += __shfl_xor(accl, 8);
        if (lane == 0) atomicAdd(out, accl);
    }
}

extern "C" void kernel_launch(void* const* d_in, const int* in_sizes, int n_in,
                              void* d_out, int out_size, void* d_ws, size_t ws_size,
                              hipStream_t stream) {
    const float* x    = (const float*)d_in[0];
    const int*   xlen = (const int*)d_in[1];
    const float* xlab = (const float*)d_in[2];
    const float* Wz   = (const float*)d_in[3];
    const float* Uz   = (const float*)d_in[4];
    const float* Wr   = (const float*)d_in[5];
    const float* Ur   = (const float*)d_in[6];
    const float* Wh   = (const float*)d_in[7];
    const float* Uh   = (const float*)d_in[8];
    const float* Wo   = (const float*)d_in[9];
    float* out = (float*)d_out;

    unsigned char* ws  = (unsigned char*)d_ws;
    unsigned char* wpU = ws;                                 // fp8 U-frags, 384 KB
    unsigned char* wpW = ws + OFF_WPW;                       // bf16 W-frags, 768 KB
    unsigned int*  XP  = (unsigned int*)(ws + OFF_XP);       // 25.2 MB
    unsigned int*  HP  = (unsigned int*)(ws + OFF_HP);       // 25.2 MB
    unsigned short* HN = (unsigned short*)(ws + OFF_HN);     // 16.8 MB

    // ws re-poisoned every call -> rebuild everything each time.
    prep_weights<<<1536, 256, 0, stream>>>(Wz, Wr, Wh, Uz, Ur, Uh, ws, out);
    proj_kernel<1><<<2048, 1024, 0, stream>>>(x, wpW, XP, 0);                         // A: x @ W(l0)
    recur_kernel<0><<<4, 1024, 0, stream>>>(XP, wpU, 0, HN, xlen, xlab, Wo, out);     // B: layer-0 scan
    proj_kernel<0><<<2048, 1024, 0, stream>>>(HN, wpW, HP, 3);                        // C: hn0 @ W(l1)
    recur_kernel<1><<<4, 1024, 0, stream>>>(HP, wpU, 3, nullptr, xlen, xlab, Wo, out);// D: layer-1 + loss
}